// Round 9
// baseline (649.116 us; speedup 1.0000x reference)
//
#include <hip/hip_runtime.h>
#include <hip/hip_bf16.h>
#include <hip/hip_fp16.h>

// 2-layer Elman RNN, S=64 B=64 H=E=512 V=10000.
// r9: software-pipelined recurrence. One mega-kernel, 24 blocks:
//   blocks 0-3  : L0 recur (r6 body), exports h0(t)->hp0 + flag0[g]=t+1
//   blocks 4-19 : W1-stage (4/group): a1(t)=h0(t)@W1^T+b -> A1p (permuted), flag1
//   blocks 20-23: L1 recur (r6 body), waits flag1, -> H1h + tail
// Pipes are one-directional, 64-deep (t-indexed) -> producer never blocks;
// fence/flag pattern identical to round-1's correctness-proven protocol.
// B1 GEMM + W1h cvt deleted; L1 fully overlaps L0.

typedef _Float16 f16;
typedef _Float16 f16x8 __attribute__((ext_vector_type(8)));
typedef float fvec4 __attribute__((ext_vector_type(4)));
typedef float f32x4 __attribute__((ext_vector_type(4)));
typedef unsigned int u32;
typedef u32 u32x2 __attribute__((ext_vector_type(2)));

#define AGENT __HIP_MEMORY_SCOPE_AGENT

__device__ __forceinline__ f32x4 mfma16(f16x8 a, f16x8 b, f32x4 c) {
    return __builtin_amdgcn_mfma_f32_16x16x32_f16(a, b, c, 0, 0, 0);
}

__device__ __forceinline__ f16x8 cvt_f16x8(fvec4 a, fvec4 b) {
    f16x8 r;
    r[0] = (f16)a[0]; r[1] = (f16)a[1]; r[2] = (f16)a[2]; r[3] = (f16)a[3];
    r[4] = (f16)b[0]; r[5] = (f16)b[1]; r[6] = (f16)b[2]; r[7] = (f16)b[3];
    return r;
}

// ---- fp32 -> f16 convert, 8 elems/thread ----
__global__ void cvt_f32_f16(const float* __restrict__ src, f16* __restrict__ dst, int n8) {
    int i = blockIdx.x * 256 + threadIdx.x;
    if (i >= n8) return;
    const fvec4* p = (const fvec4*)(src + (size_t)i * 8);
    *(f16x8*)(dst + (size_t)i * 8) = cvt_f16x8(p[0], p[1]);
}

// ---- Wd (10000x512) -> f16 padded to 10112 rows (zero pad) ----
__global__ void cvt_wd(const float* __restrict__ src, f16* __restrict__ dst) {
    int i = blockIdx.x * 256 + threadIdx.x;
    if (i >= 647168) return;
    if (i < 640000) {
        const fvec4* p = (const fvec4*)(src + (size_t)i * 8);
        *(f16x8*)(dst + (size_t)i * 8) = cvt_f16x8(p[0], p[1]);
    } else {
        f16x8 z = {};
        *(f16x8*)(dst + (size_t)i * 8) = z;
    }
}

// ---- gather X = f16(emb[tokens]) : (4096, 512) ----
__global__ void gather_x(const int* __restrict__ toks, const float* __restrict__ emb,
                         f16* __restrict__ xb) {
    int i = blockIdx.x * 256 + threadIdx.x;
    if (i >= 262144) return;
    int row = i >> 6, seg = i & 63;
    int tok = toks[row];
    const fvec4* p = (const fvec4*)(emb + (size_t)tok * 512 + seg * 8);
    *(f16x8*)(xb + (size_t)row * 512 + seg * 8) = cvt_f16x8(p[0], p[1]);
}

__global__ void zero_u32(u32* p, int n) {
    int i = blockIdx.x * 256 + threadIdx.x;
    if (i < n) p[i] = 0;
}

// ---- GEMM (round-3 proven): C = A(M,512)f16 @ Bm(Npad,512)f16^T + biases ----
// MODE 0: C row-major (M,N).  MODE 1: permuted fragment layout for recur:
// idx = (((t*4+g)*8+w)*64 + lane)*16 + nt*4 + r.
template <int MODE>
__global__ __launch_bounds__(256) void gemm_bt(
    const f16* __restrict__ A, const f16* __restrict__ Bm,
    const float* __restrict__ bias1, const float* __restrict__ bias2,
    float* __restrict__ C, int N)
{
    const int tM = blockIdx.x * 128;
    const int tN = blockIdx.y * 128;
    const int tid = threadIdx.x;
    const int l = tid & 63, w = tid >> 6;
    const int wr = w >> 1, wc = w & 1;
    const int l15 = l & 15, l4 = l >> 4;

    __shared__ f16 As[128 * 40];
    __shared__ f16 Bs[128 * 40];

    f32x4 acc[4][4] = {};

    for (int ks = 0; ks < 16; ++ks) {
        const int k0 = ks * 32;
        __syncthreads();
#pragma unroll
        for (int it = 0; it < 2; ++it) {
            int c = tid + it * 256;
            int row = c >> 2, seg = c & 3;
            *(f16x8*)(&As[row * 40 + seg * 8]) =
                *(const f16x8*)(A + (size_t)(tM + row) * 512 + k0 + seg * 8);
            *(f16x8*)(&Bs[row * 40 + seg * 8]) =
                *(const f16x8*)(Bm + (size_t)(tN + row) * 512 + k0 + seg * 8);
        }
        __syncthreads();
        f16x8 af[4], bf[4];
#pragma unroll
        for (int m = 0; m < 4; ++m)
            af[m] = *(const f16x8*)(&As[(wr * 64 + m * 16 + l15) * 40 + 8 * l4]);
#pragma unroll
        for (int n = 0; n < 4; ++n)
            bf[n] = *(const f16x8*)(&Bs[(wc * 64 + n * 16 + l15) * 40 + 8 * l4]);
#pragma unroll
        for (int m = 0; m < 4; ++m)
#pragma unroll
            for (int n = 0; n < 4; ++n)
                acc[m][n] = mfma16(af[m], bf[n], acc[m][n]);
    }

    if (MODE == 0) {
#pragma unroll
        for (int n = 0; n < 4; ++n) {
            int col = tN + wc * 64 + n * 16 + l15;
            if (col >= N) continue;
            float bsum = (bias1 ? bias1[col] : 0.f) + (bias2 ? bias2[col] : 0.f);
#pragma unroll
            for (int m = 0; m < 4; ++m)
#pragma unroll
                for (int r = 0; r < 4; ++r) {
                    int row = tM + wr * 64 + m * 16 + l4 * 4 + r;
                    C[(size_t)row * N + col] = acc[m][n][r] + bsum;
                }
        }
    } else {
        const int t  = blockIdx.x * 2 + wr;
        const int wp = blockIdx.y * 2 + wc;
        const int lp_hi = (l15 >> 2) * 16;
        const int rp = l15 & 3;
#pragma unroll
        for (int n = 0; n < 4; ++n) {
            int col = tN + wc * 64 + n * 16 + l15;
            float bsum = bias1[col] + bias2[col];
#pragma unroll
            for (int m = 0; m < 4; ++m) {
#pragma unroll
                for (int r = 0; r < 4; ++r) {
                    int lanep = lp_hi + l4 * 4 + r;
                    size_t idx = ((((size_t)t * 4 + m) * 8 + wp) * 64 + lanep) * 16
                                 + n * 4 + rp;
                    C[idx] = acc[m][n][r] + bsum;
                }
            }
        }
    }
}

// ======================= mega pipelined recurrence =======================
// ROLE 0 (L0): no wait; export h0(t) -> hp0[g][t] (row-major 16x512 f16),
//              release flag0[g]=t+1. ROLE 1 (L1): wait min_q flag1[g*4+q]>=t+1;
//              export Hh (H1h row-major). Both: r6-proven recur body.
template <int ROLE>
__device__ __forceinline__ void recur_role(
    char* smem, int g, const float* Ainp, const float* U, const float* h0,
    f16* hp0, f16* Hh, float* outTail, u32* flag0, u32* flag1)
{
    const int tid = threadIdx.x;
    const int l = tid & 63, w = tid >> 6;
    const int l15 = l & 15, l4 = l >> 4;
    const int colbase = w * 64;

    char* hsb  = smem;                // 2 x (16 rows x 1024B), XOR-swizzled
    char* ldsB = smem + 32768;        // U kk12..15: [w][nt][kk][lane*16B]

    f16x8 bf[4][12];
#pragma unroll
    for (int nt = 0; nt < 4; ++nt) {
        const float* urow = U + (size_t)(colbase + nt * 16 + l15) * 512 + 8 * l4;
#pragma unroll
        for (int kk = 0; kk < 12; ++kk) {
            const fvec4* p = (const fvec4*)(urow + kk * 32);
            bf[nt][kk] = cvt_f16x8(p[0], p[1]);
        }
#pragma unroll
        for (int kk = 12; kk < 16; ++kk) {
            const fvec4* p = (const fvec4*)(urow + kk * 32);
            *(f16x8*)(ldsB + ((w * 4 + nt) * 4 + (kk - 12)) * 1024 + l * 16) =
                cvt_f16x8(p[0], p[1]);
        }
    }
    for (int c = tid; c < 1024; c += 512) {
        int row = c >> 6, seg = c & 63;
        const fvec4* p = (const fvec4*)(h0 + (size_t)(g * 16 + row) * 512 + seg * 8);
        *(f16x8*)(hsb + row * 1024 + ((seg * 16) ^ ((row & 7) << 4))) =
            cvt_f16x8(p[0], p[1]);
    }
    __syncthreads();

    const int sw = (l15 & 7) << 4;
    const int rowbase = l15 * 1024;

    for (int t = 0; t < 64; ++t) {
        if (ROLE == 1) {
            if (tid == 0) {
#pragma unroll
                for (int q = 0; q < 4; ++q)
                    while (__hip_atomic_load(&flag1[g * 4 + q], __ATOMIC_ACQUIRE,
                                             AGENT) < (u32)(t + 1))
                        __builtin_amdgcn_s_sleep(1);
            }
            __syncthreads();
        }

        const float* ab = Ainp + (((size_t)t * 4 + g) * 8 + w) * 1024 + l * 16;
        f32x4 acc[4];
#pragma unroll
        for (int nt = 0; nt < 4; ++nt) acc[nt] = *(const fvec4*)(ab + nt * 4);

        const char* hrd = hsb + (t & 1) * 16384 + rowbase;
#pragma unroll
        for (int kk = 0; kk < 12; ++kk) {
            f16x8 h = *(const f16x8*)(hrd + ((kk * 64 + l4 * 16) ^ sw));
            acc[0] = mfma16(bf[0][kk], h, acc[0]);
            acc[1] = mfma16(bf[1][kk], h, acc[1]);
            acc[2] = mfma16(bf[2][kk], h, acc[2]);
            acc[3] = mfma16(bf[3][kk], h, acc[3]);
        }
#pragma unroll
        for (int kk = 12; kk < 16; ++kk) {
            f16x8 h = *(const f16x8*)(hrd + ((kk * 64 + l4 * 16) ^ sw));
#pragma unroll
            for (int nt = 0; nt < 4; ++nt) {
                f16x8 u = *(const f16x8*)(ldsB + ((w * 4 + nt) * 4 + (kk - 12)) * 1024 + l * 16);
                acc[nt] = mfma16(u, h, acc[nt]);
            }
        }

        char* hwr = hsb + (((t & 1) ^ 1) * 16384) + rowbase;
        f16* hrow = (ROLE == 0)
            ? hp0 + ((size_t)(g * 64 + t)) * 8192 + l15 * 512
            : Hh + ((size_t)t * 64 + g * 16 + l15) * 512;
#pragma unroll
        for (int nt = 0; nt < 4; ++nt) {
            f32x4 v;
#pragma unroll
            for (int r = 0; r < 4; ++r) {
                float x = acc[nt][r];
                float e = __expf(2.0f * x);
                v[r] = 1.0f - 2.0f * __builtin_amdgcn_rcpf(e + 1.0f);
            }
            f16 h0c = (f16)v[0], h1c = (f16)v[1], h2c = (f16)v[2], h3c = (f16)v[3];
            u32 p0 = ((u32)__builtin_bit_cast(unsigned short, h1c) << 16) |
                     (u32)__builtin_bit_cast(unsigned short, h0c);
            u32 p1 = ((u32)__builtin_bit_cast(unsigned short, h3c) << 16) |
                     (u32)__builtin_bit_cast(unsigned short, h2c);
            u32x2 pk; pk[0] = p0; pk[1] = p1;
            int c0 = colbase + nt * 16 + l4 * 4;
            *(u32x2*)(hwr + ((c0 * 2) ^ sw)) = pk;
            *(u32x2*)(hrow + c0) = pk;
            if (t == 63)
                *(f32x4*)(outTail + (size_t)(g * 16 + l15) * 512 + c0) = v;
        }
        if (ROLE == 0) __threadfence();
        __syncthreads();
        if (ROLE == 0 && tid == 0)
            __hip_atomic_store(&flag0[g], (u32)(t + 1), __ATOMIC_RELEASE, AGENT);
    }
}

__global__ __launch_bounds__(512) void mega_recur(
    const float* __restrict__ A0p, float* __restrict__ A1p,
    const float* __restrict__ U0, const float* __restrict__ U1,
    const float* __restrict__ W1,
    const float* __restrict__ bW1, const float* __restrict__ bU1,
    const float* __restrict__ hidden,
    f16* __restrict__ hp0, f16* __restrict__ H1h,
    float* __restrict__ outT, u32* __restrict__ flags)
{
    __shared__ __align__(16) char smem[163840];
    u32* flag0 = flags;          // [4]
    u32* flag1 = flags + 4;      // [16]
    const int bid = blockIdx.x;

    if (bid < 4) {
        recur_role<0>(smem, bid, A0p, U0, hidden, hp0, nullptr,
                      outT, flag0, flag1);
    } else if (bid < 20) {
        // ---- W1-stage: a1 = h0(t) @ W1^T + bW1 + bU1, 128 cols per block ----
        const int g = (bid - 4) >> 2, q = (bid - 4) & 3;
        const int tid = threadIdx.x;
        const int l = tid & 63, wv = tid >> 6;
        const int l15 = l & 15, l4 = l >> 4;
        const int sw = (l15 & 7) << 4;

        // W1 fragments resident in VGPRs (64/lane): wave wv owns 16 cols
        f16x8 wf[16];
        {
            const float* wrow = W1 + (size_t)(q * 128 + wv * 16 + l15) * 512 + 8 * l4;
#pragma unroll
            for (int kk = 0; kk < 16; ++kk) {
                const fvec4* p = (const fvec4*)(wrow + kk * 32);
                wf[kk] = cvt_f16x8(p[0], p[1]);
            }
        }
        const int colb = q * 128 + wv * 16 + l4 * 4;
        fvec4 bsum = *(const fvec4*)(bW1 + colb);
        bsum += *(const fvec4*)(bU1 + colb);

        const int wdst = q * 2 + (wv >> 2);
        const int ntd  = wv & 3;

        for (int t = 0; t < 64; ++t) {
            if (tid == 0) {
                while (__hip_atomic_load(&flag0[g], __ATOMIC_ACQUIRE, AGENT) <
                       (u32)(t + 1))
                    __builtin_amdgcn_s_sleep(1);
            }
            __syncthreads();
            // stage h0(t) 16x512 f16 -> swizzled LDS dbuf
            const f16* hsrc = hp0 + ((size_t)(g * 64 + t)) * 8192;
            char* hb = smem + (t & 1) * 16384;
            for (int c = tid; c < 1024; c += 512) {
                int row = c >> 6, seg = c & 63;
                *(f16x8*)(hb + row * 1024 + ((seg * 16) ^ ((row & 7) << 4))) =
                    *(const f16x8*)(hsrc + row * 512 + seg * 8);
            }
            __syncthreads();

            f32x4 acc = bsum;
            const char* hrd = hb + l15 * 1024;
#pragma unroll
            for (int kk = 0; kk < 16; ++kk) {
                f16x8 h = *(const f16x8*)(hrd + ((kk * 64 + l4 * 16) ^ sw));
                acc = mfma16(wf[kk], h, acc);
            }
            float* dst = A1p + ((((size_t)t * 4 + g) * 8 + wdst) * 64 + l) * 16 + ntd * 4;
            *(f32x4*)dst = acc;
            __threadfence();
            __syncthreads();
            if (tid == 0)
                __hip_atomic_fetch_add(&flag1[g * 4 + q], 1u, __ATOMIC_RELEASE, AGENT);
        }
    } else {
        recur_role<1>(smem, bid - 20, A1p, U1, hidden + 32768, nullptr, H1h,
                      outT + 32768, flag0, flag1);
    }
}

extern "C" void kernel_launch(void* const* d_in, const int* in_sizes, int n_in,
                              void* d_out, int out_size, void* d_ws, size_t ws_size,
                              hipStream_t stream) {
    const int*   toks   = (const int*)d_in[0];
    const float* hidden = (const float*)d_in[1];
    const float* emb    = (const float*)d_in[2];
    const float* W0  = (const float*)d_in[3];
    const float* bW0 = (const float*)d_in[4];
    const float* W1  = (const float*)d_in[5];
    const float* bW1 = (const float*)d_in[6];
    const float* U0  = (const float*)d_in[7];
    const float* bU0 = (const float*)d_in[8];
    const float* U1  = (const float*)d_in[9];
    const float* bU1 = (const float*)d_in[10];
    const float* Wd  = (const float*)d_in[11];
    const float* bd  = (const float*)d_in[12];
    float* out = (float*)d_out;

    char* ws = (char*)d_ws;
    f16*   W0h  = (f16*)(ws + 0);               // 524288
    f16*   Wdh  = (f16*)(ws + 1048576);         // 10354688
    f16*   Xb   = (f16*)(ws + 11403264);        // 4194304
    f16*   hp0  = (f16*)(ws + 15597568);        // 4194304 (4 groups x 64 t x 16KB)
    f16*   H1h  = (f16*)(ws + 19791872);        // 4194304
    float* A0   = (float*)(ws + 23986176);      // 8388608 (permuted)
    float* A1p  = (float*)(ws + 32374784);      // 8388608 (permuted)
    u32*   flags= (u32*)(ws + 40763392);        // 80 B

    cvt_f32_f16<<<128, 256, 0, stream>>>(W0, W0h, 32768);
    cvt_wd<<<2528, 256, 0, stream>>>(Wd, Wdh);
    gather_x<<<1024, 256, 0, stream>>>(toks, emb, Xb);
    zero_u32<<<1, 256, 0, stream>>>(flags, 20);

    // A0 = perm(X @ W0^T + bW0 + bU0)
    gemm_bt<1><<<dim3(32, 4), 256, 0, stream>>>(Xb, W0h, bW0, bU0, A0, 512);
    // pipelined L0 -> W1-stage -> L1 (24 blocks, co-resident)
    mega_recur<<<24, 512, 0, stream>>>(A0, A1p, U0, U1, W1, bW1, bU1, hidden,
                                       hp0, H1h, out + 40960000, flags);
    // logits = H1 @ Wd^T + bd
    gemm_bt<0><<<dim3(32, 79), 256, 0, stream>>>(H1h, Wdh, bd, nullptr, out, 10000);
}